// Round 9
// baseline (182.220 us; speedup 1.0000x reference)
//
#include <hip/hip_runtime.h>
#include <math.h>

#define BATCH 32
#define SEQ   8192
#define HID   512
#define STRIPES 16                        // pass1 blocks per batch
#define RPB   (SEQ / STRIPES)             // 512 rows per block
#define CR    16                          // chunk rows (32 KB per chunk)
#define NCHUNK (RPB / CR)                 // 32 chunks

typedef float f4 __attribute__((ext_vector_type(4)));

#define VMWAIT(N) do { asm volatile("s_waitcnt vmcnt(" #N ")" ::: "memory"); \
                       __builtin_amdgcn_sched_barrier(0); } while (0)
#define LGKMWAIT0 do { asm volatile("s_waitcnt lgkmcnt(0)" ::: "memory"); \
                       __builtin_amdgcn_sched_barrier(0); } while (0)

__device__ __forceinline__ void gload_lds(const float* g, float* l) {
  __builtin_amdgcn_global_load_lds(
      (const __attribute__((address_space(1))) void*)g,
      (__attribute__((address_space(3))) void*)l, 16, 0, 0);
}

// Pass 1: fused attn-dot + raw-attn store + masked softmax partials.
// R4 structure (best: per-wave private pipeline, counted vmcnt, no main-loop
// barriers, 2 blocks/CU, aux=0). NEW: chunk-deferred softmax — one online
// merge per 4-row chunk instead of 4 serial per-row rescales.
__global__ __launch_bounds__(256, 2) void k_pass1(
    const float* __restrict__ outp, const float* __restrict__ ctx,
    const int* __restrict__ split, float* __restrict__ attn_out,
    float* __restrict__ pacc, float* __restrict__ pmd)
{
  __shared__ float lds[2][CR][HID];       // 2 x 32 KB
  const int tid = threadIdx.x, lane = tid & 63, wave = tid >> 6;
  const int b = blockIdx.x >> 4;          // STRIPES == 16
  const int stripe = blockIdx.x & 15;
  const int sp = split[b];
  const int s_base = stripe * RPB;

  const float* ob = outp + b * HID + lane * 8;
  const f4 o0 = *(const f4*)ob;
  const f4 o1 = *(const f4*)(ob + 4);

  const float* cbase = ctx + ((size_t)b * SEQ + s_base) * HID;
  float* ao = attn_out + (size_t)b * SEQ + s_base;

  // prologue: chunk0 -> buf0, chunk1 -> buf1 (own wave region: rows 4w..4w+3)
#pragma unroll
  for (int i = 0; i < 8; ++i) {
    const int o = (wave * 8 + i) * 256;
    gload_lds(cbase + o + lane * 4, &lds[0][0][0] + o);
  }
#pragma unroll
  for (int i = 0; i < 8; ++i) {
    const int o = (wave * 8 + i) * 256;
    gload_lds(cbase + CR * HID + o + lane * 4, &lds[1][0][0] + o);
  }

  float m = -INFINITY, d = 0.f;
  f4 acc0 = {0.f, 0.f, 0.f, 0.f}, acc1 = {0.f, 0.f, 0.f, 0.f};

  // vmcnt ledger (in-order retirement); iter issues: L(c+2)x8 then st(c).
  //   iter 0: queue = L0(8),L1(8)=16                    -> wait 8
  //   iter c: queue = L(c)8,st(c-2),L(c+1)8,st(c-1)=18  -> wait 9
  //   last  : queue = L(31)8,st(29),st(30)=10           -> wait 1
#pragma unroll 1
  for (int c = 0; c < NCHUNK; ++c) {
    if (c == 0)                 VMWAIT(8);
    else if (c == NCHUNK - 1)   VMWAIT(1);
    else                        VMWAIT(9);

    const int cur = c & 1;
    f4 c0[4], c1[4];
#pragma unroll
    for (int k = 0; k < 4; ++k) {
      const float* rp = &lds[cur][wave * 4 + k][lane * 8];
      c0[k] = *(const f4*)rp;
      c1[k] = *(const f4*)(rp + 4);
    }
    LGKMWAIT0;   // rows now in regs -> safe to overwrite buf[cur]

    if (c + 2 < NCHUNK) {       // prefetch chunk c+2 into buf[cur]
      const float* src = cbase + (size_t)(c + 2) * CR * HID;
      float* dst = &lds[cur][0][0];
#pragma unroll
      for (int i = 0; i < 8; ++i) {
        const int o = (wave * 8 + i) * 256;
        gload_lds(src + o + lane * 4, dst + o);
      }
    }

    float a4[4];
#pragma unroll
    for (int k = 0; k < 4; ++k) {
      float v = o0[0]*c0[k][0] + o0[1]*c0[k][1] + o0[2]*c0[k][2] + o0[3]*c0[k][3]
              + o1[0]*c1[k][0] + o1[1]*c1[k][1] + o1[2]*c1[k][2] + o1[3]*c1[k][3];
#pragma unroll
      for (int off = 32; off >= 1; off >>= 1) v += __shfl_xor(v, off, 64);
      a4[k] = v;                // full butterfly: all lanes hold row-sum
    }
    if (lane == 0) {
      f4 st = {a4[0], a4[1], a4[2], a4[3]};
      *(f4*)(ao + c * CR + wave * 4) = st;   // raw attn (1 vmem store/iter)
    }

    // chunk-deferred masked softmax: one merge per 4-row chunk
    {
      const int s0 = s_base + c * CR + wave * 4;   // wave-uniform
      const float am0 = (s0 + 0 < sp) ? a4[0] : -INFINITY;
      const float am1 = (s0 + 1 < sp) ? a4[1] : -INFINITY;
      const float am2 = (s0 + 2 < sp) ? a4[2] : -INFINITY;
      const float am3 = (s0 + 3 < sp) ? a4[3] : -INFINITY;
      const float cm = fmaxf(fmaxf(am0, am1), fmaxf(am2, am3));
      if (cm != -INFINITY) {                       // wave-uniform
        const float w0 = __expf(am0 - cm), w1 = __expf(am1 - cm);
        const float w2 = __expf(am2 - cm), w3 = __expf(am3 - cm);
        const float dc = (w0 + w1) + (w2 + w3);
        const f4 ac0 = (w0 * c0[0] + w1 * c0[1]) + (w2 * c0[2] + w3 * c0[3]);
        const f4 ac1 = (w0 * c1[0] + w1 * c1[1]) + (w2 * c1[2] + w3 * c1[3]);
        const float nm = fmaxf(m, cm);
        const float e1 = __expf(m - nm);           // m=-inf -> e1=0
        const float e2 = __expf(cm - nm);
        d = d * e1 + dc * e2;
        acc0 = acc0 * e1 + ac0 * e2;
        acc1 = acc1 * e1 + ac1 * e2;
        m = nm;
      }
    }
  }

  __syncthreads();                        // all waves done with buffers
  float* lacc = &lds[0][0][0];            // [4][HID]
  float* lmd  = &lds[1][0][0];            // [4][2]
  *(f4*)(lacc + wave * HID + lane * 8)     = acc0;
  *(f4*)(lacc + wave * HID + lane * 8 + 4) = acc1;
  if (lane == 0) { lmd[wave * 2] = m; lmd[wave * 2 + 1] = d; }
  __syncthreads();

  const float M = fmaxf(fmaxf(lmd[0], lmd[2]), fmaxf(lmd[4], lmd[6]));
  const size_t pb = (size_t)b * STRIPES + stripe;
  float* pa = pacc + pb * HID;
  if (M == -INFINITY) {
    pa[tid * 2] = 0.f; pa[tid * 2 + 1] = 0.f;
    if (tid == 0) { pmd[pb * 2] = -INFINITY; pmd[pb * 2 + 1] = 0.f; }
  } else {
    float e[4], Dl = 0.f;
#pragma unroll
    for (int wv = 0; wv < 4; ++wv) {
      const float mw = lmd[wv * 2];
      e[wv] = (mw == -INFINITY) ? 0.f : __expf(mw - M);
      Dl += e[wv] * lmd[wv * 2 + 1];
    }
    float s0 = 0.f, s1 = 0.f;
#pragma unroll
    for (int wv = 0; wv < 4; ++wv) {
      s0 += e[wv] * lacc[wv * HID + tid * 2];
      s1 += e[wv] * lacc[wv * HID + tid * 2 + 1];
    }
    pa[tid * 2] = s0; pa[tid * 2 + 1] = s1;
    if (tid == 0) { pmd[pb * 2] = M; pmd[pb * 2 + 1] = Dl; }
  }
}

// Tail A: per batch, merge stripe partials -> combined[b][2048] =
// [amix, amix, det_row, output_row]  (reference concat order).
__global__ __launch_bounds__(256) void k_combine(
    const float* __restrict__ outp, const float* __restrict__ ctx,
    const int* __restrict__ split, const float* __restrict__ pacc,
    const float* __restrict__ pmd, float* __restrict__ combined)
{
  const int b = blockIdx.x, tid = threadIdx.x;
  float M = -INFINITY;
#pragma unroll
  for (int c = 0; c < STRIPES; ++c) M = fmaxf(M, pmd[(b * STRIPES + c) * 2]);
  float wgt[STRIPES], D = 0.f;
#pragma unroll
  for (int c = 0; c < STRIPES; ++c) {
    const float mw = pmd[(b * STRIPES + c) * 2];
    wgt[c] = (mw == -INFINITY) ? 0.f : __expf(mw - M);
    D += wgt[c] * pmd[(b * STRIPES + c) * 2 + 1];
  }
  const float invD = 1.f / D;
  const int sp = split[b];
  float* cb = combined + (size_t)b * (4 * HID);
#pragma unroll
  for (int col = tid; col < HID; col += 256) {   // 2 iters
    float s = 0.f;
#pragma unroll
    for (int c = 0; c < STRIPES; ++c)
      s += wgt[c] * pacc[((size_t)(b * STRIPES + c)) * HID + col];
    const float am = s * invD;
    cb[col]           = am;
    cb[HID + col]     = am;                       // b_mix == a_mix (ref bug)
    cb[2 * HID + col] = ctx[((size_t)b * SEQ + sp) * HID + col];
    cb[3 * HID + col] = outp[b * HID + col];
  }
}

// Tail B: GEMV reading W exactly once. Block g holds 8 W-rows (h = g*8+r)
// in registers (16 f4/thread); loops over all 32 batches' combined vectors
// (256 KB total, L2-resident). tid = r*32 + t; t covers 64 k-cols.
__global__ __launch_bounds__(256) void k_gemv(
    const float* __restrict__ W, const float* __restrict__ bias,
    const float* __restrict__ combined, float* __restrict__ out0)
{
  const int g = blockIdx.x;            // 64 blocks
  const int r = threadIdx.x >> 5, t = threadIdx.x & 31;
  const int h = g * 8 + r;

  f4 wreg[16];
  const float* wr = W + (size_t)h * (4 * HID) + t * 64;
#pragma unroll
  for (int i = 0; i < 16; ++i) wreg[i] = *(const f4*)(wr + i * 4);
  const float bi = bias[h];

#pragma unroll 1
  for (int b = 0; b < BATCH; ++b) {
    const float* cb = combined + (size_t)b * (4 * HID) + t * 64;
    float acc = 0.f;
#pragma unroll
    for (int i = 0; i < 16; ++i) {
      const f4 x = *(const f4*)(cb + i * 4);
      acc += wreg[i][0]*x[0] + wreg[i][1]*x[1] + wreg[i][2]*x[2] + wreg[i][3]*x[3];
    }
#pragma unroll
    for (int off = 16; off >= 1; off >>= 1) acc += __shfl_xor(acc, off, 64);
    if (t == 0) out0[b * HID + h] = tanhf(acc + bi);
  }
}

extern "C" void kernel_launch(void* const* d_in, const int* in_sizes, int n_in,
                              void* d_out, int out_size, void* d_ws, size_t ws_size,
                              hipStream_t stream)
{
  const float* outp = (const float*)d_in[0]; // [B,1,H] f32
  const float* ctx  = (const float*)d_in[1]; // [B,S,H] f32
  const int*   spl  = (const int*)d_in[2];   // [B] int32
  const float* W    = (const float*)d_in[3]; // [H,4H] f32
  const float* bias = (const float*)d_in[4]; // [H] f32

  float* out0   = (float*)d_out;                        // B*H f32
  float* attn_o = out0 + (size_t)BATCH * HID;           // B*S f32

  float* pacc     = (float*)d_ws;                       // B*STRIPES*HID f32 (1 MB)
  float* pmd      = pacc + (size_t)BATCH * STRIPES * HID;  // B*STRIPES*2 f32
  float* combined = pmd + (size_t)BATCH * STRIPES * 2;  // B*4H f32 (256 KB)

  k_pass1  <<<BATCH * STRIPES, 256, 0, stream>>>(outp, ctx, spl, attn_o, pacc, pmd);
  k_combine<<<BATCH,           256, 0, stream>>>(outp, ctx, spl, pacc, pmd, combined);
  k_gemv   <<<64,              256, 0, stream>>>(W, bias, combined, out0);
}

// Round 10
// 126.002 us; speedup vs baseline: 1.4462x; 1.4462x over previous
//
#include <hip/hip_runtime.h>
#include <math.h>

#define BATCH 32
#define SEQ   8192
#define HID   512
#define STRIPES 32                        // pass1 blocks per batch
#define RPB   (SEQ / STRIPES)             // 256 rows per block
#define CR    8                           // chunk rows (16 KB per chunk)
#define NBUF  3                           // ring buffers
#define NCHUNK (RPB / CR)                 // 32 chunks

typedef float f4 __attribute__((ext_vector_type(4)));
typedef float f2 __attribute__((ext_vector_type(2)));

#define VMWAIT(N) do { asm volatile("s_waitcnt vmcnt(" #N ")" ::: "memory"); \
                       __builtin_amdgcn_sched_barrier(0); } while (0)

__device__ __forceinline__ void gload_lds(const float* g, float* l) {
  __builtin_amdgcn_global_load_lds(
      (const __attribute__((address_space(1))) void*)g,
      (__attribute__((address_space(3))) void*)l, 16, 0, 0);
}

// Pass 1: fused attn-dot + raw-attn store + online masked softmax partials.
// RING-OF-3 LDS buffers: prefetch target (c+2)%3 is never the read buffer
// (c%3) nor the in-flight one ((c+1)%3) -> no overwrite hazard, NO lgkm
// drain before prefetch-issue; prefetch issues FIRST in each iteration.
// Per-wave private pipeline (wave w owns rows 2w,2w+1 of each chunk),
// counted vmcnt, no main-loop barriers. 48 KB LDS -> 3 blocks/CU.
__global__ __launch_bounds__(256, 3) void k_pass1(
    const float* __restrict__ outp, const float* __restrict__ ctx,
    const int* __restrict__ split, float* __restrict__ attn_out,
    float* __restrict__ pacc, float* __restrict__ pmd)
{
  __shared__ float lds[NBUF][CR][HID];    // 3 x 16 KB
  const int tid = threadIdx.x, lane = tid & 63, wave = tid >> 6;
  const int b = blockIdx.x >> 5;          // STRIPES == 32
  const int stripe = blockIdx.x & 31;
  const int sp = split[b];
  const int s_base = stripe * RPB;

  const float* ob = outp + b * HID + lane * 8;
  const f4 o0 = *(const f4*)ob;
  const f4 o1 = *(const f4*)(ob + 4);

  const float* cbase = ctx + ((size_t)b * SEQ + s_base) * HID;
  float* ao = attn_out + (size_t)b * SEQ + s_base;

  // prologue: chunk0 -> buf0, chunk1 -> buf1 (own wave region: rows 2w,2w+1)
#pragma unroll
  for (int i = 0; i < 4; ++i) {
    const int o = (wave * 4 + i) * 256;
    gload_lds(cbase + o + lane * 4, &lds[0][0][0] + o);
  }
#pragma unroll
  for (int i = 0; i < 4; ++i) {
    const int o = (wave * 4 + i) * 256;
    gload_lds(cbase + CR * HID + o + lane * 4, &lds[1][0][0] + o);
  }

  float m = -INFINITY, d = 0.f;
  f4 acc0 = {0.f, 0.f, 0.f, 0.f}, acc1 = {0.f, 0.f, 0.f, 0.f};

  // vmcnt ledger (in-order retirement); iter issues: L(c+2)x4 then st(c).
  //   entry iter 0: L(0)4,L(1)4                         -> wait 4
  //   entry iter 1: L(1)4,L(2)4,st(0)                   -> wait 5
  //   entry iter c: L(c)4,st(c-2),L(c+1)4,st(c-1) = 10  -> wait 6
  //   entry last  : L(31)4,st(29),st(30)                -> wait 2
#pragma unroll 1
  for (int c = 0; c < NCHUNK; ++c) {
    if (c == 0)                 VMWAIT(4);
    else if (c == 1)            VMWAIT(5);
    else if (c == NCHUNK - 1)   VMWAIT(2);
    else                        VMWAIT(6);

    if (c + 2 < NCHUNK) {       // prefetch chunk c+2 FIRST (ring: no hazard)
      const float* src = cbase + (size_t)(c + 2) * CR * HID;
      float* dst = &lds[(c + 2) % NBUF][0][0];
#pragma unroll
      for (int i = 0; i < 4; ++i) {
        const int o = (wave * 4 + i) * 256;
        gload_lds(src + o + lane * 4, dst + o);
      }
    }

    const int cur = c % NBUF;
    f4 c0[2], c1[2];
#pragma unroll
    for (int k = 0; k < 2; ++k) {
      const float* rp = &lds[cur][wave * 2 + k][lane * 8];
      c0[k] = *(const f4*)rp;
      c1[k] = *(const f4*)(rp + 4);
    }

    float a2[2];
#pragma unroll
    for (int k = 0; k < 2; ++k) {
      float v = o0[0]*c0[k][0] + o0[1]*c0[k][1] + o0[2]*c0[k][2] + o0[3]*c0[k][3]
              + o1[0]*c1[k][0] + o1[1]*c1[k][1] + o1[2]*c1[k][2] + o1[3]*c1[k][3];
#pragma unroll
      for (int off = 32; off >= 1; off >>= 1) v += __shfl_xor(v, off, 64);
      a2[k] = v;
    }
    if (lane == 0) {
      f2 st = {a2[0], a2[1]};
      *(f2*)(ao + c * CR + wave * 2) = st;   // raw attn (1 vmem store/iter)
    }

#pragma unroll
    for (int k = 0; k < 2; ++k) {
      const int s = s_base + c * CR + wave * 2 + k;  // wave-uniform branch
      if (s < sp) {
        const float v  = a2[k];
        const float nm = fmaxf(m, v);
        const float sc = __expf(m - nm);
        const float w  = __expf(v - nm);
        d = d * sc + w;
        acc0 = acc0 * sc + w * c0[k];
        acc1 = acc1 * sc + w * c1[k];
        m = nm;
      }
    }
  }

  __syncthreads();                        // all waves done with buffers
  float* lacc = &lds[0][0][0];            // [4][HID] (reuse buffer 0)
  float* lmd  = &lds[1][0][0];            // [4][2]   (reuse buffer 1)
  *(f4*)(lacc + wave * HID + lane * 8)     = acc0;
  *(f4*)(lacc + wave * HID + lane * 8 + 4) = acc1;
  if (lane == 0) { lmd[wave * 2] = m; lmd[wave * 2 + 1] = d; }
  __syncthreads();

  const float M = fmaxf(fmaxf(lmd[0], lmd[2]), fmaxf(lmd[4], lmd[6]));
  const size_t pb = (size_t)b * STRIPES + stripe;
  float* pa = pacc + pb * HID;
  if (M == -INFINITY) {
    pa[tid * 2] = 0.f; pa[tid * 2 + 1] = 0.f;
    if (tid == 0) { pmd[pb * 2] = -INFINITY; pmd[pb * 2 + 1] = 0.f; }
  } else {
    float e[4], Dl = 0.f;
#pragma unroll
    for (int wv = 0; wv < 4; ++wv) {
      const float mw = lmd[wv * 2];
      e[wv] = (mw == -INFINITY) ? 0.f : __expf(mw - M);
      Dl += e[wv] * lmd[wv * 2 + 1];
    }
    float s0 = 0.f, s1 = 0.f;
#pragma unroll
    for (int wv = 0; wv < 4; ++wv) {
      s0 += e[wv] * lacc[wv * HID + tid * 2];
      s1 += e[wv] * lacc[wv * HID + tid * 2 + 1];
    }
    pa[tid * 2] = s0; pa[tid * 2 + 1] = s1;
    if (tid == 0) { pmd[pb * 2] = M; pmd[pb * 2 + 1] = Dl; }
  }
}

// Pass 2 (R4-proven form): block (b,q) -> 64 outputs. 4-way k-split per h
// (tid = hl*4+part); parts: 0,1 -> amix halves; 2 -> det; 3 -> output.
__global__ __launch_bounds__(256) void k_final(
    const float* __restrict__ outp, const float* __restrict__ ctx,
    const int* __restrict__ split, const float* __restrict__ W,
    const float* __restrict__ bias, const float* __restrict__ pacc,
    const float* __restrict__ pmd, float* __restrict__ out0)
{
  const int b = blockIdx.x >> 3, q = blockIdx.x & 7;
  const int tid = threadIdx.x;
  __shared__ float comb[3 * HID + 8];
  float* amixp = comb;                 // [0, 512)
  float* detp  = comb + HID + 4;       // bank offset +4
  float* oupp  = comb + 2 * HID + 8;   // bank offset +8

  float M = -INFINITY;
#pragma unroll
  for (int c = 0; c < STRIPES; ++c) M = fmaxf(M, pmd[(b * STRIPES + c) * 2]);
  float wgt[STRIPES], D = 0.f;
#pragma unroll
  for (int c = 0; c < STRIPES; ++c) {
    const float mw = pmd[(b * STRIPES + c) * 2];
    wgt[c] = (mw == -INFINITY) ? 0.f : __expf(mw - M);
    D += wgt[c] * pmd[(b * STRIPES + c) * 2 + 1];
  }
  const float invD = 1.f / D;
  const int sp = split[b];
#pragma unroll
  for (int col = tid; col < HID; col += 256) {
    float s = 0.f;
#pragma unroll
    for (int c = 0; c < STRIPES; ++c)
      s += wgt[c] * pacc[((size_t)(b * STRIPES + c)) * HID + col];
    amixp[col] = s * invD;
    detp[col]  = ctx[((size_t)b * SEQ + sp) * HID + col];
    oupp[col]  = outp[b * HID + col];
  }
  __syncthreads();

  const int hl = tid >> 2, part = tid & 3;
  const int h = q * 64 + hl;
  const float* wr = W + (size_t)h * (4 * HID) + part * HID;
  const float* src = (part == 2) ? detp : (part == 3 ? oupp : amixp);
  float acc = 0.f;
#pragma unroll 4
  for (int k0 = 0; k0 < HID; k0 += 4) {
    const f4 w = *(const f4*)(wr + k0);
    const f4 x = *(const f4*)(src + k0);
    acc += w[0]*x[0] + w[1]*x[1] + w[2]*x[2] + w[3]*x[3];
  }
  acc += __shfl_xor(acc, 1, 64);
  acc += __shfl_xor(acc, 2, 64);
  if (part == 0) out0[b * HID + h] = tanhf(acc + bias[h]);
}

extern "C" void kernel_launch(void* const* d_in, const int* in_sizes, int n_in,
                              void* d_out, int out_size, void* d_ws, size_t ws_size,
                              hipStream_t stream)
{
  const float* outp = (const float*)d_in[0]; // [B,1,H] f32
  const float* ctx  = (const float*)d_in[1]; // [B,S,H] f32
  const int*   spl  = (const int*)d_in[2];   // [B] int32
  const float* W    = (const float*)d_in[3]; // [H,4H] f32
  const float* bias = (const float*)d_in[4]; // [H] f32

  float* out0   = (float*)d_out;                        // B*H f32
  float* attn_o = out0 + (size_t)BATCH * HID;           // B*S f32

  float* pacc = (float*)d_ws;                           // B*STRIPES*HID f32 (2 MB)
  float* pmd  = pacc + (size_t)BATCH * STRIPES * HID;   // B*STRIPES*2 f32

  k_pass1<<<BATCH * STRIPES, 256, 0, stream>>>(outp, ctx, spl, attn_o, pacc, pmd);
  k_final<<<BATCH * 8,       256, 0, stream>>>(outp, ctx, spl, W, bias, pacc, pmd, out0);
}

// Round 11
// 122.469 us; speedup vs baseline: 1.4879x; 1.0288x over previous
//
#include <hip/hip_runtime.h>
#include <math.h>

#define BATCH 32
#define SEQ   8192
#define HID   512
#define STRIPES 16                        // pass1 blocks per batch
#define RPB   (SEQ / STRIPES)             // 512 rows per block
#define CR    16                          // chunk rows (32 KB per chunk)
#define NCHUNK (RPB / CR)                 // 32 chunks

typedef float f4 __attribute__((ext_vector_type(4)));

#define VMWAIT(N) do { asm volatile("s_waitcnt vmcnt(" #N ")" ::: "memory"); \
                       __builtin_amdgcn_sched_barrier(0); } while (0)
#define LGKMWAIT0 do { asm volatile("s_waitcnt lgkmcnt(0)" ::: "memory"); \
                       __builtin_amdgcn_sched_barrier(0); } while (0)

__device__ __forceinline__ void gload_lds(const float* g, float* l) {
  __builtin_amdgcn_global_load_lds(
      (const __attribute__((address_space(1))) void*)g,
      (__attribute__((address_space(3))) void*)l, 16, 0, 0);
}

// Pass 1: fused attn-dot + raw-attn store + online masked softmax partials.
// Per-wave private pipeline: wave w stages ONLY rows 4w..4w+3 of each chunk
// (global_load_lds, 2 chunks in flight), so NO barriers in the main loop —
// just counted s_waitcnt vmcnt(N) per wave (T4). Best measured config (R4).
__global__ __launch_bounds__(256, 2) void k_pass1(
    const float* __restrict__ outp, const float* __restrict__ ctx,
    const int* __restrict__ split, float* __restrict__ attn_out,
    float* __restrict__ pacc, float* __restrict__ pmd)
{
  __shared__ float lds[2][CR][HID];       // 2 x 32 KB
  const int tid = threadIdx.x, lane = tid & 63, wave = tid >> 6;
  const int b = blockIdx.x >> 4;          // STRIPES == 16
  const int stripe = blockIdx.x & 15;
  const int sp = split[b];
  const int s_base = stripe * RPB;

  const float* ob = outp + b * HID + lane * 8;
  const f4 o0 = *(const f4*)ob;
  const f4 o1 = *(const f4*)(ob + 4);

  const float* cbase = ctx + ((size_t)b * SEQ + s_base) * HID;
  float* ao = attn_out + (size_t)b * SEQ + s_base;

  // prologue: chunk0 -> buf0, chunk1 -> buf1 (own wave region: rows 4w..4w+3)
#pragma unroll
  for (int i = 0; i < 8; ++i) {
    const int o = (wave * 8 + i) * 256;
    gload_lds(cbase + o + lane * 4, &lds[0][0][0] + o);
  }
#pragma unroll
  for (int i = 0; i < 8; ++i) {
    const int o = (wave * 8 + i) * 256;
    gload_lds(cbase + CR * HID + o + lane * 4, &lds[1][0][0] + o);
  }

  float m = -INFINITY, d = 0.f;
  f4 acc0 = {0.f, 0.f, 0.f, 0.f}, acc1 = {0.f, 0.f, 0.f, 0.f};

#pragma unroll 1
  for (int c = 0; c < NCHUNK; ++c) {
    // wait for chunk c's 8 loads (oldest); robust to store/load order per iter
    if (c == 0)                 VMWAIT(8);
    else if (c == NCHUNK - 1)   VMWAIT(1);
    else                        VMWAIT(9);

    const int cur = c & 1;
    f4 c0[4], c1[4];
#pragma unroll
    for (int k = 0; k < 4; ++k) {
      const float* rp = &lds[cur][wave * 4 + k][lane * 8];
      c0[k] = *(const f4*)rp;
      c1[k] = *(const f4*)(rp + 4);
    }
    LGKMWAIT0;   // rows now in regs -> safe to overwrite buf[cur]

    if (c + 2 < NCHUNK) {       // prefetch chunk c+2 into buf[cur]
      const float* src = cbase + (size_t)(c + 2) * CR * HID;
      float* dst = &lds[cur][0][0];
#pragma unroll
      for (int i = 0; i < 8; ++i) {
        const int o = (wave * 8 + i) * 256;
        gload_lds(src + o + lane * 4, dst + o);
      }
    }

    float a4[4];
#pragma unroll
    for (int k = 0; k < 4; ++k) {
      float v = o0[0]*c0[k][0] + o0[1]*c0[k][1] + o0[2]*c0[k][2] + o0[3]*c0[k][3]
              + o1[0]*c1[k][0] + o1[1]*c1[k][1] + o1[2]*c1[k][2] + o1[3]*c1[k][3];
#pragma unroll
      for (int off = 32; off >= 1; off >>= 1) v += __shfl_xor(v, off, 64);
      a4[k] = v;
    }
    if (lane == 0) {
      f4 st = {a4[0], a4[1], a4[2], a4[3]};
      *(f4*)(ao + c * CR + wave * 4) = st;   // raw attn (1 vmem store/iter)
    }
#pragma unroll
    for (int k = 0; k < 4; ++k) {
      const int s = s_base + c * CR + wave * 4 + k;  // wave-uniform branch
      if (s < sp) {
        const float v  = a4[k];
        const float nm = fmaxf(m, v);
        const float sc = __expf(m - nm);
        const float w  = __expf(v - nm);
        d = d * sc + w;
        acc0 = acc0 * sc + w * c0[k];
        acc1 = acc1 * sc + w * c1[k];
        m = nm;
      }
    }
  }

  __syncthreads();                        // all waves done with buffers
  float* lacc = &lds[0][0][0];            // [4][HID]
  float* lmd  = &lds[1][0][0];            // [4][2]
  *(f4*)(lacc + wave * HID + lane * 8)     = acc0;
  *(f4*)(lacc + wave * HID + lane * 8 + 4) = acc1;
  if (lane == 0) { lmd[wave * 2] = m; lmd[wave * 2 + 1] = d; }
  __syncthreads();

  const float M = fmaxf(fmaxf(lmd[0], lmd[2]), fmaxf(lmd[4], lmd[6]));
  const size_t pb = (size_t)b * STRIPES + stripe;
  float* pa = pacc + pb * HID;
  if (M == -INFINITY) {
    pa[tid * 2] = 0.f; pa[tid * 2 + 1] = 0.f;
    if (tid == 0) { pmd[pb * 2] = -INFINITY; pmd[pb * 2 + 1] = 0.f; }
  } else {
    float e[4], Dl = 0.f;
#pragma unroll
    for (int wv = 0; wv < 4; ++wv) {
      const float mw = lmd[wv * 2];
      e[wv] = (mw == -INFINITY) ? 0.f : __expf(mw - M);
      Dl += e[wv] * lmd[wv * 2 + 1];
    }
    float s0 = 0.f, s1 = 0.f;
#pragma unroll
    for (int wv = 0; wv < 4; ++wv) {
      s0 += e[wv] * lacc[wv * HID + tid * 2];
      s1 += e[wv] * lacc[wv * HID + tid * 2 + 1];
    }
    pa[tid * 2] = s0; pa[tid * 2 + 1] = s1;
    if (tid == 0) { pmd[pb * 2] = M; pmd[pb * 2 + 1] = Dl; }
  }
}

// Pass 2: block (b,q) -> 64 outputs. 4-way k-split per h (tid = hl*4+part),
// parts: 0,1 -> amix halves of W row; 2 -> det; 3 -> output. LDS bank-padded.
__global__ __launch_bounds__(256) void k_final(
    const float* __restrict__ outp, const float* __restrict__ ctx,
    const int* __restrict__ split, const float* __restrict__ W,
    const float* __restrict__ bias, const float* __restrict__ pacc,
    const float* __restrict__ pmd, float* __restrict__ out0)
{
  const int b = blockIdx.x >> 3, q = blockIdx.x & 7;
  const int tid = threadIdx.x;
  __shared__ float comb[3 * HID + 8];
  float* amixp = comb;                 // [0, 512)
  float* detp  = comb + HID + 4;       // bank offset +4
  float* oupp  = comb + 2 * HID + 8;   // bank offset +8

  float M = -INFINITY;
#pragma unroll
  for (int c = 0; c < STRIPES; ++c) M = fmaxf(M, pmd[(b * STRIPES + c) * 2]);
  float wgt[STRIPES], D = 0.f;
#pragma unroll
  for (int c = 0; c < STRIPES; ++c) {
    const float mw = pmd[(b * STRIPES + c) * 2];
    wgt[c] = (mw == -INFINITY) ? 0.f : __expf(mw - M);
    D += wgt[c] * pmd[(b * STRIPES + c) * 2 + 1];
  }
  const float invD = 1.f / D;
  const int sp = split[b];
#pragma unroll
  for (int col = tid; col < HID; col += 256) {
    float s = 0.f;
#pragma unroll
    for (int c = 0; c < STRIPES; ++c)
      s += wgt[c] * pacc[((size_t)(b * STRIPES + c)) * HID + col];
    amixp[col] = s * invD;
    detp[col]  = ctx[((size_t)b * SEQ + sp) * HID + col];
    oupp[col]  = outp[b * HID + col];
  }
  __syncthreads();

  const int hl = tid >> 2, part = tid & 3;
  const int h = q * 64 + hl;
  const float* wr = W + (size_t)h * (4 * HID) + part * HID;
  const float* src = (part == 2) ? detp : (part == 3 ? oupp : amixp);
  float acc = 0.f;
#pragma unroll 4
  for (int k0 = 0; k0 < HID; k0 += 4) {
    const f4 w = *(const f4*)(wr + k0);
    const f4 x = *(const f4*)(src + k0);
    acc += w[0]*x[0] + w[1]*x[1] + w[2]*x[2] + w[3]*x[3];
  }
  acc += __shfl_xor(acc, 1, 64);
  acc += __shfl_xor(acc, 2, 64);
  if (part == 0) out0[b * HID + h] = tanhf(acc + bias[h]);
}

extern "C" void kernel_launch(void* const* d_in, const int* in_sizes, int n_in,
                              void* d_out, int out_size, void* d_ws, size_t ws_size,
                              hipStream_t stream)
{
  const float* outp = (const float*)d_in[0]; // [B,1,H] f32
  const float* ctx  = (const float*)d_in[1]; // [B,S,H] f32
  const int*   spl  = (const int*)d_in[2];   // [B] int32
  const float* W    = (const float*)d_in[3]; // [H,4H] f32
  const float* bias = (const float*)d_in[4]; // [H] f32

  float* out0   = (float*)d_out;                        // B*H f32
  float* attn_o = out0 + (size_t)BATCH * HID;           // B*S f32

  float* pacc = (float*)d_ws;                           // B*STRIPES*HID f32 (1 MB)
  float* pmd  = pacc + (size_t)BATCH * STRIPES * HID;   // B*STRIPES*2 f32

  k_pass1<<<BATCH * STRIPES, 256, 0, stream>>>(outp, ctx, spl, attn_o, pacc, pmd);
  k_final<<<BATCH * 8,       256, 0, stream>>>(outp, ctx, spl, W, bias, pacc, pmd, out0);
}